// Round 13
// baseline (3753.366 us; speedup 1.0000x reference)
//
#include <hip/hip_runtime.h>
#include <stdint.h>

typedef __attribute__((ext_vector_type(8))) short short8;
typedef __attribute__((ext_vector_type(4))) float f32x4;

#define NT 15
#define RW 32     // rows per block

// packed bf16 weight fragments in d_ws (element offsets, shorts)
#define SET0 0          // L0: 32 (jt,g) pairs x 5 kt x 512
#define SET1 81920      // L1: 32 pairs x 8 kt x 512
#define SET2 212992     // dec: same shape as L1
#define SET3 344064
#define PK_TOTAL 346112
#define DD_OFF (PK_TOTAL*2)   // dbase[1280] | hw[768] | hb[6] | hc[6]  (floats)

__device__ __forceinline__ unsigned short f2bf(float f){
  unsigned int u = __builtin_bit_cast(unsigned int, f);
  u += 0x7fffu + ((u >> 16) & 1u);
  return (unsigned short)(u >> 16);
}
__device__ __forceinline__ float sigf(float x){
  return __builtin_amdgcn_rcpf(1.0f + __expf(-x));
}
__device__ __forceinline__ float tanhf_(float x){
  return 1.0f - 2.0f*__builtin_amdgcn_rcpf(1.0f + __expf(2.0f*x));
}
__device__ __forceinline__ int sidx(int row, int col){
  return row*128 + (col ^ ((row & 7) << 3));
}
__device__ __forceinline__ void BAR(){
  asm volatile("s_waitcnt lgkmcnt(0)" ::: "memory");
  __builtin_amdgcn_s_barrier();
}

// ---------------- prep: pack weights to bf16 MFMA fragments ----------------
__global__ void pack_w(const float* __restrict__ Wih0, const float* __restrict__ Whh0,
                       const float* __restrict__ Wih1, const float* __restrict__ Whh1,
                       const float* __restrict__ Wihd, const float* __restrict__ Whhd,
                       const float* __restrict__ Wm,  const float* __restrict__ Ws,
                       unsigned short* __restrict__ pk)
{
  int idx = blockIdx.x*256 + threadIdx.x;
  if (idx >= PK_TOTAL) return;
  float v = 0.f;
  if (idx >= SET3){
    int e = idx - SET3;
    int j = e & 7, lane = (e >> 3) & 63, kt = e >> 9;
    int n = lane & 15;
    int k = kt*32 + (lane >> 4)*8 + j;
    if (n < 3) v = Wm[n*128 + k];
    else if (n < 6) v = Ws[(n-3)*128 + k];
  } else {
    int set, e;
    if (idx < SET1){ set = 0; e = idx; }
    else if (idx < SET2){ set = 1; e = idx - SET1; }
    else { set = 2; e = idx - SET2; }
    int j = e & 7, lane = (e >> 3) & 63, rest = e >> 9;
    int nf = (set == 0) ? 5 : 8;
    int kt = rest % nf, pair = rest / nf;
    int g = pair & 3, jt = pair >> 2;
    int n = g*128 + jt*16 + (lane & 15);
    int kk = (lane >> 4)*8 + j;
    if (set == 0){
      if (kt < 4) v = Whh0[n*128 + kt*32 + kk];
      else if (kk < 6) v = Wih0[n*6 + kk];
    } else {
      const float* Wi = (set == 1) ? Wih1 : Wihd;
      const float* Wh = (set == 1) ? Whh1 : Whhd;
      v = (kt < 4) ? Wi[n*128 + kt*32 + kk] : Wh[n*128 + (kt-4)*32 + kk];
    }
  }
  pk[idx] = f2bf(v);
}

// decoder constants (see r7)
__global__ void prep_dec(const float* __restrict__ emb, const float* __restrict__ Wp,
                         const float* __restrict__ bp,
                         const float* __restrict__ Wm, const float* __restrict__ Ws,
                         const float* __restrict__ bm, const float* __restrict__ bs,
                         const float* __restrict__ lng, const float* __restrict__ lnb,
                         float* __restrict__ dd)
{
  int idx = blockIdx.x*128 + threadIdx.x;
  if (idx < 1280){
    int s = idx >> 7, j = idx & 127;
    float acc = bp[j];
    for (int k = 0; k < 128; ++k) acc += emb[s*128 + k] * Wp[j*131 + 3 + k];
    dd[idx] = acc;
  } else if (idx < 2048){
    int e = idx - 1280; int o = e >> 7, j = e & 127;
    const float* W = (o < 3) ? (Wm + o*128) : (Ws + (o-3)*128);
    dd[idx] = W[j] * lng[j];
  } else if (idx < 2054){
    int o = idx - 2048;
    const float* W = (o < 3) ? (Wm + o*128) : (Ws + (o-3)*128);
    float a = 0.f;
    for (int k = 0; k < 128; ++k) a += W[k]*lng[k];
    dd[idx] = a;
  } else if (idx < 2060){
    int o = idx - 2054;
    const float* W = (o < 3) ? (Wm + o*128) : (Ws + (o-3)*128);
    float a = (o < 3) ? bm[o] : bs[o-3];
    for (int k = 0; k < 128; ++k) a += W[k]*lnb[k];
    dd[idx] = a;
  }
}

// ---------------- main fused kernel ----------------
// r13 = r12 + __launch_bounds__(256, 3): unified reg budget 170/wave.
// r12 proved the 256-thr/RW=32 structure is SPILL-FREE at VGPR=208
// (WRITE 15MB = compulsory, FETCH 14.5MB) but 208 regs -> 1 wave/SIMD
// (Occ 12%) was pure latency exposure. The 208 was mostly hoisted
// weight-load depth; capping to 170 trades hoisting for 3 waves/SIMD
// (3 blocks/CU, 3 independent barrier domains).
__global__ __launch_bounds__(256, 3)
void traj_main(const float* __restrict__ x,
               const unsigned short* __restrict__ pk,
               const float* __restrict__ dd,
               const float* __restrict__ b0g, const float* __restrict__ b1g,
               const float* __restrict__ bdg,
               const float* __restrict__ Wp,
               float* __restrict__ out)
{
  __shared__ __align__(16) union {
    unsigned short h[2][RW*128];                      // h0 ping-pong / h[0]=din
    struct {
      unsigned short pad[RW*128];                     // = h[0] (din region)
      float sred[4][RW][8];                           // overlays h[1] (dec-dead)
      float prevb[RW][4];
    } d;
  } uA;
  __shared__ __align__(16) unsigned short hB[2][RW*128];  // h1 ping-pong
  __shared__ __align__(16) union {
    unsigned short xs[NT*RW*8];                       // 7680 B (encoder)
    struct { float om[RW][30]; float os[RW][30]; } o; // 7680 B (decoder)
  } u2;

  const int tid  = threadIdx.x;
  const int w    = tid >> 6;
  const int lane = tid & 63;
  const int lidx = lane & 15;
  const int lgrp = lane >> 4;
  const int row0 = blockIdx.x * RW;

  for (int i = tid; i < RW*128; i += 256){ uA.h[1][i] = 0; hB[1][i] = 0; }
  for (int i = tid; i < NT*RW*8; i += 256){
    int k8 = i & 7, rt = i >> 3;
    int r = rt & (RW-1), t = rt >> 5;
    u2.xs[i] = (k8 < 6) ? f2bf(x[(size_t)(row0 + r)*90 + t*6 + k8])
                        : (unsigned short)0;
  }

  int colv[2]; colv[0] = w*32 + lidx; colv[1] = w*32 + 16 + lidx;
  float b0v[2][4], b1v[2][4];
  #pragma unroll
  for (int j2 = 0; j2 < 2; ++j2)
    #pragma unroll
    for (int g = 0; g < 4; ++g){
      b0v[j2][g] = b0g[g*128 + colv[j2]];
      b1v[j2][g] = b1g[g*128 + colv[j2]];
    }

  float c0[2][2][4], c1[2][2][4];
  #pragma unroll
  for (int j2 = 0; j2 < 2; ++j2)
    #pragma unroll
    for (int m = 0; m < 2; ++m)
      #pragma unroll
      for (int r = 0; r < 4; ++r){ c0[j2][m][r] = 0.f; c1[j2][m][r] = 0.f; }

  __syncthreads();

  const unsigned short* pw0 = pk + SET0 + (w*8)*(5*512) + lane*8;
  const unsigned short* pw1 = pk + SET1 + (w*8)*(8*512) + lane*8;
  const unsigned short* pw2 = pk + SET2 + (w*8)*(8*512) + lane*8;
  const short8 z8 = {0,0,0,0,0,0,0,0};

  // ======== pipelined encoder: phase k = L0(k) + L1(k-1) ========
  #pragma unroll 1
  for (int k = 0; k <= NT; ++k){
    const unsigned short* h0rd = &uA.h[(k+1)&1][0];
    unsigned short*       h0wr = &uA.h[k&1][0];
    const unsigned short* h1rd = &hB[k&1][0];
    unsigned short*       h1wr = &hB[(k+1)&1][0];

    if (k < NT){
      #pragma unroll
      for (int j2 = 0; j2 < 2; ++j2){
        f32x4 acc[2][4];
        #pragma unroll
        for (int m = 0; m < 2; ++m)
          #pragma unroll
          for (int g = 0; g < 4; ++g)
            acc[m][g] = (f32x4){b0v[j2][g], b0v[j2][g], b0v[j2][g], b0v[j2][g]};
        #pragma unroll
        for (int kt = 0; kt < 5; ++kt){
          short8 am[2];
          #pragma unroll
          for (int m = 0; m < 2; ++m){
            const int arow = m*16 + lidx;
            if (kt < 4)
              am[m] = *(const short8*)&h0rd[sidx(arow, kt*32 + lgrp*8)];
            else
              am[m] = (lgrp == 0) ? *(const short8*)&u2.xs[(k*RW + arow)*8] : z8;
          }
          #pragma unroll
          for (int g = 0; g < 4; ++g){
            short8 wv = *(const short8*)&pw0[((j2*4 + g)*5 + kt)*512];
            #pragma unroll
            for (int m = 0; m < 2; ++m)
              acc[m][g] = __builtin_amdgcn_mfma_f32_16x16x32_bf16(am[m], wv, acc[m][g], 0, 0, 0);
          }
        }
        #pragma unroll
        for (int m = 0; m < 2; ++m)
          #pragma unroll
          for (int r = 0; r < 4; ++r){
            float iv = sigf(acc[m][0][r]);
            float fv = sigf(acc[m][1][r]);
            float gv = tanhf_(acc[m][2][r]);
            float ov = sigf(acc[m][3][r]);
            float c = fv*c0[j2][m][r] + iv*gv;
            c0[j2][m][r] = c;
            h0wr[sidx(m*16 + lgrp*4 + r, colv[j2])] = f2bf(ov*tanhf_(c));
          }
      }
    }

    if (k >= 1){
      #pragma unroll
      for (int j2 = 0; j2 < 2; ++j2){
        f32x4 acc[2][4];
        #pragma unroll
        for (int m = 0; m < 2; ++m)
          #pragma unroll
          for (int g = 0; g < 4; ++g)
            acc[m][g] = (f32x4){b1v[j2][g], b1v[j2][g], b1v[j2][g], b1v[j2][g]};
        #pragma unroll
        for (int kt = 0; kt < 8; ++kt){
          short8 am[2];
          #pragma unroll
          for (int m = 0; m < 2; ++m){
            const int arow = m*16 + lidx;
            if (kt < 4)
              am[m] = *(const short8*)&h0rd[sidx(arow, kt*32 + lgrp*8)];
            else
              am[m] = *(const short8*)&h1rd[sidx(arow, (kt-4)*32 + lgrp*8)];
          }
          #pragma unroll
          for (int g = 0; g < 4; ++g){
            short8 wv = *(const short8*)&pw1[((j2*4 + g)*8 + kt)*512];
            #pragma unroll
            for (int m = 0; m < 2; ++m)
              acc[m][g] = __builtin_amdgcn_mfma_f32_16x16x32_bf16(am[m], wv, acc[m][g], 0, 0, 0);
          }
        }
        #pragma unroll
        for (int m = 0; m < 2; ++m)
          #pragma unroll
          for (int r = 0; r < 4; ++r){
            float iv = sigf(acc[m][0][r]);
            float fv = sigf(acc[m][1][r]);
            float gv = tanhf_(acc[m][2][r]);
            float ov = sigf(acc[m][3][r]);
            float c = fv*c1[j2][m][r] + iv*gv;
            c1[j2][m][r] = c;
            h1wr[sidx(m*16 + lgrp*4 + r, colv[j2])] = f2bf(ov*tanhf_(c));
          }
      }
    }
    BAR();
  }
  // h1[14] in hB[0]; uA.h[*] dead as h0 -> overlay becomes live.

  // ===================== decoder =====================
  const float* dbase = dd;
  const float* hwp   = dd + 1280;
  const float* hbp   = dd + 2048;
  const float* hcp   = dd + 2054;

  float wp3[2][3], bdv[2][4], hwv[2][6];
  #pragma unroll
  for (int j2 = 0; j2 < 2; ++j2){
    #pragma unroll
    for (int o = 0; o < 3; ++o) wp3[j2][o] = Wp[colv[j2]*131 + o];
    #pragma unroll
    for (int g = 0; g < 4; ++g) bdv[j2][g] = bdg[g*128 + colv[j2]];
    #pragma unroll
    for (int o = 0; o < 6; ++o) hwv[j2][o] = hwp[o*128 + colv[j2]];
  }
  float hbv[6], hcv[6];
  #pragma unroll
  for (int o = 0; o < 6; ++o){ hbv[o] = hbp[o]; hcv[o] = hcp[o]; }

  if (tid < RW*3){
    int r = tid / 3, o = tid - r*3;
    uA.d.prevb[r][o] = x[(size_t)(row0 + r)*90 + 14*6 + o];
  }
  __syncthreads();   // overlay role switch + u2 xs -> om/os

  int hcur = 0, hnew = 1;
  #pragma unroll 1
  for (int s = 0; s < 10; ++s){
    unsigned short* bdin = &uA.h[0][0];
    const unsigned short* bh = &hB[hcur][0];
    unsigned short* bhn = &hB[hnew][0];

    // ph1: dec_in = relu(dbase + prev @ Wp3^T) -> uA.h[0]
    #pragma unroll
    for (int j2 = 0; j2 < 2; ++j2){
      const float dbs = dbase[s*128 + colv[j2]];
      #pragma unroll
      for (int m = 0; m < 2; ++m)
        #pragma unroll
        for (int r = 0; r < 4; ++r){
          const int row = m*16 + lgrp*4 + r;
          f32x4 pv = *(const f32x4*)&uA.d.prevb[row][0];
          float v = dbs + pv[0]*wp3[j2][0] + pv[1]*wp3[j2][1] + pv[2]*wp3[j2][2];
          bdin[sidx(row, colv[j2])] = f2bf(v > 0.f ? v : 0.f);
        }
    }
    BAR();

    // ph2: LSTM cell (jt2-outer) + fused LN/head partials
    float hreg[2][2][4];
    #pragma unroll
    for (int j2 = 0; j2 < 2; ++j2){
      f32x4 acc[2][4];
      #pragma unroll
      for (int m = 0; m < 2; ++m)
        #pragma unroll
        for (int g = 0; g < 4; ++g)
          acc[m][g] = (f32x4){bdv[j2][g], bdv[j2][g], bdv[j2][g], bdv[j2][g]};
      #pragma unroll
      for (int kt = 0; kt < 8; ++kt){
        short8 am[2];
        #pragma unroll
        for (int m = 0; m < 2; ++m){
          const int arow = m*16 + lidx;
          if (kt < 4)
            am[m] = *(const short8*)&bdin[sidx(arow, kt*32 + lgrp*8)];
          else
            am[m] = *(const short8*)&bh[sidx(arow, (kt-4)*32 + lgrp*8)];
        }
        #pragma unroll
        for (int g = 0; g < 4; ++g){
          short8 wv = *(const short8*)&pw2[((j2*4 + g)*8 + kt)*512];
          #pragma unroll
          for (int m = 0; m < 2; ++m)
            acc[m][g] = __builtin_amdgcn_mfma_f32_16x16x32_bf16(am[m], wv, acc[m][g], 0, 0, 0);
        }
      }
      #pragma unroll
      for (int m = 0; m < 2; ++m)
        #pragma unroll
        for (int r = 0; r < 4; ++r){
          float iv = sigf(acc[m][0][r]);
          float fv = sigf(acc[m][1][r]);
          float gv = tanhf_(acc[m][2][r]);
          float ov = sigf(acc[m][3][r]);
          float c = fv*c1[j2][m][r] + iv*gv;
          c1[j2][m][r] = c;
          float h = ov*tanhf_(c);
          hreg[j2][m][r] = h;
          bhn[sidx(m*16 + lgrp*4 + r, colv[j2])] = f2bf(h);
        }
    }
    // LN/head partials: combine both jt2 cols, shuffle over lidx
    #pragma unroll
    for (int m = 0; m < 2; ++m)
      #pragma unroll
      for (int r = 0; r < 4; ++r){
        float h0 = hreg[0][m][r], h1 = hreg[1][m][r];
        float vals[8];
        vals[0] = h0 + h1;
        vals[1] = h0*h0 + h1*h1;
        #pragma unroll
        for (int o = 0; o < 6; ++o) vals[2+o] = h0*hwv[0][o] + h1*hwv[1][o];
        #pragma unroll
        for (int d = 1; d < 16; d <<= 1)
          #pragma unroll
          for (int kk = 0; kk < 8; ++kk)
            vals[kk] += __shfl_xor(vals[kk], d);
        if (lidx == 0){
          const int row = m*16 + lgrp*4 + r;
          *(f32x4*)&uA.d.sred[w][row][0] = (f32x4){vals[0], vals[1], vals[2], vals[3]};
          *(f32x4*)&uA.d.sred[w][row][4] = (f32x4){vals[4], vals[5], vals[6], vals[7]};
        }
      }
    BAR();

    // ph3: per-row finalize
    if (tid < RW){
      float s1 = 0.f, s2 = 0.f;
      float A[6] = {0.f, 0.f, 0.f, 0.f, 0.f, 0.f};
      #pragma unroll
      for (int ww = 0; ww < 4; ++ww){
        f32x4 v0 = *(const f32x4*)&uA.d.sred[ww][tid][0];
        f32x4 v1 = *(const f32x4*)&uA.d.sred[ww][tid][4];
        s1 += v0[0]; s2 += v0[1];
        A[0] += v0[2]; A[1] += v0[3];
        A[2] += v1[0]; A[3] += v1[1]; A[4] += v1[2]; A[5] += v1[3];
      }
      float mu = s1 * (1.f/128.f);
      float var = s2 * (1.f/128.f) - mu*mu;
      float rs = __builtin_amdgcn_rsqf(var + 1e-5f);
      #pragma unroll
      for (int o = 0; o < 3; ++o){
        float v = rs*(A[o] - mu*hbv[o]) + hcv[o];
        u2.o.om[tid][s*3 + o] = v;
        uA.d.prevb[tid][o] = v;
      }
      #pragma unroll
      for (int o = 3; o < 6; ++o){
        float v = rs*(A[o] - mu*hbv[o]) + hcv[o];
        u2.o.os[tid][s*3 + (o-3)] = fminf(fmaxf(v, -6.f), 3.f);
      }
    }
    BAR();
    int tswap = hcur; hcur = hnew; hnew = tswap;
  }

  // ---- single coalesced output flush ----
  for (int i = tid; i < RW*30; i += 256){
    int r = i / 30, cx = i - r*30;
    out[(size_t)(row0 + r)*30 + cx] = u2.o.om[r][cx];
    out[(size_t)65536*30 + (size_t)(row0 + r)*30 + cx] = u2.o.os[r][cx];
  }
}

extern "C" void kernel_launch(void* const* d_in, const int* in_sizes, int n_in,
                              void* d_out, int out_size, void* d_ws, size_t ws_size,
                              hipStream_t stream)
{
  const float* x    = (const float*)d_in[0];
  const float* Wih0 = (const float*)d_in[1];
  const float* Whh0 = (const float*)d_in[2];
  const float* b0   = (const float*)d_in[3];
  const float* Wih1 = (const float*)d_in[4];
  const float* Whh1 = (const float*)d_in[5];
  const float* b1   = (const float*)d_in[6];
  const float* Wihd = (const float*)d_in[7];
  const float* Whhd = (const float*)d_in[8];
  const float* bd   = (const float*)d_in[9];
  const float* emb  = (const float*)d_in[10];
  const float* Wp   = (const float*)d_in[11];
  const float* bp   = (const float*)d_in[12];
  const float* Wm   = (const float*)d_in[13];
  const float* bm   = (const float*)d_in[14];
  const float* Ws   = (const float*)d_in[15];
  const float* bs   = (const float*)d_in[16];
  const float* lng  = (const float*)d_in[17];
  const float* lnb  = (const float*)d_in[18];

  unsigned short* pkw = (unsigned short*)d_ws;
  float* dd = (float*)((char*)d_ws + DD_OFF);

  pack_w<<<(PK_TOTAL + 255)/256, 256, 0, stream>>>(Wih0, Whh0, Wih1, Whh1,
                                                   Wihd, Whhd, Wm, Ws, pkw);
  prep_dec<<<17, 128, 0, stream>>>(emb, Wp, bp, Wm, Ws, bm, bs, lng, lnb, dd);
  traj_main<<<65536/RW, 256, 0, stream>>>(x, pkw, dd, b0, b1, bd, Wp, (float*)d_out);
}

// Round 14
// 1991.958 us; speedup vs baseline: 1.8843x; 1.8843x over previous
//
#include <hip/hip_runtime.h>
#include <stdint.h>

typedef __attribute__((ext_vector_type(8))) short short8;
typedef __attribute__((ext_vector_type(4))) float f32x4;

#define NT 15

// packed bf16 weight fragments in d_ws (element offsets, shorts)
#define SET0 0          // L0: 32 (jt,g) pairs x 5 kt x 512
#define SET1 81920      // L1: 32 pairs x 8 kt x 512
#define SET2 212992     // dec: same shape as L1
#define SET3 344064
#define PK_TOTAL 346112
#define DD_OFF (PK_TOTAL*2)   // dbase[1280] | hw[768] | hb[6] | hc[6]  (floats)

__device__ __forceinline__ unsigned short f2bf(float f){
  unsigned int u = __builtin_bit_cast(unsigned int, f);
  u += 0x7fffu + ((u >> 16) & 1u);
  return (unsigned short)(u >> 16);
}
__device__ __forceinline__ float sigf(float x){
  return __builtin_amdgcn_rcpf(1.0f + __expf(-x));
}
__device__ __forceinline__ float tanhf_(float x){
  return 1.0f - 2.0f*__builtin_amdgcn_rcpf(1.0f + __expf(2.0f*x));
}
__device__ __forceinline__ int sidx(int row, int col){
  return row*128 + (col ^ ((row & 7) << 3));
}
__device__ __forceinline__ void BAR(){
  asm volatile("s_waitcnt lgkmcnt(0)" ::: "memory");
  __builtin_amdgcn_s_barrier();
}

// ---------------- prep: pack weights to bf16 MFMA fragments ----------------
__global__ void pack_w(const float* __restrict__ Wih0, const float* __restrict__ Whh0,
                       const float* __restrict__ Wih1, const float* __restrict__ Whh1,
                       const float* __restrict__ Wihd, const float* __restrict__ Whhd,
                       const float* __restrict__ Wm,  const float* __restrict__ Ws,
                       unsigned short* __restrict__ pk)
{
  int idx = blockIdx.x*256 + threadIdx.x;
  if (idx >= PK_TOTAL) return;
  float v = 0.f;
  if (idx >= SET3){
    int e = idx - SET3;
    int j = e & 7, lane = (e >> 3) & 63, kt = e >> 9;
    int n = lane & 15;
    int k = kt*32 + (lane >> 4)*8 + j;
    if (n < 3) v = Wm[n*128 + k];
    else if (n < 6) v = Ws[(n-3)*128 + k];
  } else {
    int set, e;
    if (idx < SET1){ set = 0; e = idx; }
    else if (idx < SET2){ set = 1; e = idx - SET1; }
    else { set = 2; e = idx - SET2; }
    int j = e & 7, lane = (e >> 3) & 63, rest = e >> 9;
    int nf = (set == 0) ? 5 : 8;
    int kt = rest % nf, pair = rest / nf;
    int g = pair & 3, jt = pair >> 2;
    int n = g*128 + jt*16 + (lane & 15);
    int kk = (lane >> 4)*8 + j;
    if (set == 0){
      if (kt < 4) v = Whh0[n*128 + kt*32 + kk];
      else if (kk < 6) v = Wih0[n*6 + kk];
    } else {
      const float* Wi = (set == 1) ? Wih1 : Wihd;
      const float* Wh = (set == 1) ? Whh1 : Whhd;
      v = (kt < 4) ? Wi[n*128 + kt*32 + kk] : Wh[n*128 + (kt-4)*32 + kk];
    }
  }
  pk[idx] = f2bf(v);
}

// decoder constants (see r7)
__global__ void prep_dec(const float* __restrict__ emb, const float* __restrict__ Wp,
                         const float* __restrict__ bp,
                         const float* __restrict__ Wm, const float* __restrict__ Ws,
                         const float* __restrict__ bm, const float* __restrict__ bs,
                         const float* __restrict__ lng, const float* __restrict__ lnb,
                         float* __restrict__ dd)
{
  int idx = blockIdx.x*128 + threadIdx.x;
  if (idx < 1280){
    int s = idx >> 7, j = idx & 127;
    float acc = bp[j];
    for (int k = 0; k < 128; ++k) acc += emb[s*128 + k] * Wp[j*131 + 3 + k];
    dd[idx] = acc;
  } else if (idx < 2048){
    int e = idx - 1280; int o = e >> 7, j = e & 127;
    const float* W = (o < 3) ? (Wm + o*128) : (Ws + (o-3)*128);
    dd[idx] = W[j] * lng[j];
  } else if (idx < 2054){
    int o = idx - 2048;
    const float* W = (o < 3) ? (Wm + o*128) : (Ws + (o-3)*128);
    float a = 0.f;
    for (int k = 0; k < 128; ++k) a += W[k]*lng[k];
    dd[idx] = a;
  } else if (idx < 2060){
    int o = idx - 2054;
    const float* W = (o < 3) ? (Wm + o*128) : (Ws + (o-3)*128);
    float a = (o < 3) ? bm[o] : bs[o-3];
    for (int k = 0; k < 128; ++k) a += W[k]*lnb[k];
    dd[idx] = a;
  }
}

// ---------------- main fused kernel ----------------
// r14 = r11 encoder (proven best) + ONE-BARRIER decoder steps:
//   phase(s): [redundant per-lane finalize of step s-1 from sred (dbuf'd)]
//             -> prev in regs -> din A-fragments computed IN-REG (no din
//             LDS buffer, no ph1 barrier) -> cell MFMA -> sred partials
//             -> BAR. Decoder 30 phases -> 11. Thin phases (ph1/ph3) were
//             paying full barrier+latency cost for ~5% of the work.
__global__ __launch_bounds__(512)
void traj_main(const float* __restrict__ x,
               const unsigned short* __restrict__ pk,
               const float* __restrict__ dd,
               const float* __restrict__ b0g, const float* __restrict__ b1g,
               const float* __restrict__ bdg,
               const float* __restrict__ Wp,
               float* __restrict__ out)
{
  __shared__ __align__(16) union {
    unsigned short h0[2][64*128];                 // encoder h0 ping-pong (32KB)
    struct {
      float sred[2][8][64][8];                    // dbuf'd partials (32KB)
      float wp3[128][4];                          // Wp[:, :3] staged (2KB)
      float dbl[10][128];                         // dbase staged (5KB)
    } d;
  } uA;
  __shared__ __align__(16) unsigned short hB[2][64*128];  // h1 ping-pong (32KB)
  __shared__ __align__(16) union {
    unsigned short xs[NT*64*8];                       // 15360B (encoder)
    struct { float om[64][30]; float os[64][30]; } o; // 15360B (decoder)
  } u2;

  const int tid  = threadIdx.x;
  const int w    = tid >> 6;
  const int lane = tid & 63;
  const int lidx = lane & 15;
  const int lgrp = lane >> 4;
  const int col  = w*16 + lidx;
  const int row0 = blockIdx.x * 64;

  for (int i = tid; i < 64*128; i += 512){ uA.h0[1][i] = 0; hB[1][i] = 0; }
  for (int i = tid; i < NT*64*8; i += 512){
    int k8 = i & 7, rt = i >> 3;
    int r = rt & 63, t = rt >> 6;
    u2.xs[i] = (k8 < 6) ? f2bf(x[(size_t)(row0 + r)*90 + t*6 + k8])
                        : (unsigned short)0;
  }

  float b0v[4], b1v[4];
  #pragma unroll
  for (int g = 0; g < 4; ++g){ b0v[g] = b0g[g*128 + col]; b1v[g] = b1g[g*128 + col]; }

  float c0[4][4], c1[4][4];
  #pragma unroll
  for (int m = 0; m < 4; ++m)
    #pragma unroll
    for (int r = 0; r < 4; ++r){ c0[m][r] = 0.f; c1[m][r] = 0.f; }

  __syncthreads();

  const unsigned short* pw0 = pk + SET0 + (w*4)*(5*512) + lane*8;
  const unsigned short* pw1 = pk + SET1 + (w*4)*(8*512) + lane*8;
  const unsigned short* pw2 = pk + SET2 + (w*4)*(8*512) + lane*8;
  const short8 z8 = {0,0,0,0,0,0,0,0};

  // ======== pipelined encoder: phase k = L0(k) + L1(k-1), 16 phases ========
  #pragma unroll 1
  for (int k = 0; k <= NT; ++k){
    const unsigned short* h0rd = &uA.h0[(k+1)&1][0];
    unsigned short*       h0wr = &uA.h0[k&1][0];
    const unsigned short* h1rd = &hB[k&1][0];
    unsigned short*       h1wr = &hB[(k+1)&1][0];

    if (k < NT){
      f32x4 acc[4][4];
      #pragma unroll
      for (int m = 0; m < 4; ++m)
        #pragma unroll
        for (int g = 0; g < 4; ++g)
          acc[m][g] = (f32x4){b0v[g], b0v[g], b0v[g], b0v[g]};
      #pragma unroll
      for (int kt = 0; kt < 5; ++kt){
        short8 am[4];
        #pragma unroll
        for (int m = 0; m < 4; ++m){
          const int arow = m*16 + lidx;
          if (kt < 4)
            am[m] = *(const short8*)&h0rd[sidx(arow, kt*32 + lgrp*8)];
          else
            am[m] = (lgrp == 0) ? *(const short8*)&u2.xs[(k*64 + arow)*8] : z8;
        }
        #pragma unroll
        for (int g = 0; g < 4; ++g){
          short8 wv = *(const short8*)&pw0[(g*5 + kt)*512];
          #pragma unroll
          for (int m = 0; m < 4; ++m)
            acc[m][g] = __builtin_amdgcn_mfma_f32_16x16x32_bf16(am[m], wv, acc[m][g], 0, 0, 0);
        }
      }
      #pragma unroll
      for (int m = 0; m < 4; ++m)
        #pragma unroll
        for (int r = 0; r < 4; ++r){
          float iv = sigf(acc[m][0][r]);
          float fv = sigf(acc[m][1][r]);
          float gv = tanhf_(acc[m][2][r]);
          float ov = sigf(acc[m][3][r]);
          float c = fv*c0[m][r] + iv*gv;
          c0[m][r] = c;
          h0wr[sidx(m*16 + lgrp*4 + r, col)] = f2bf(ov*tanhf_(c));
        }
    }

    if (k >= 1){
      f32x4 acc[4][4];
      #pragma unroll
      for (int m = 0; m < 4; ++m)
        #pragma unroll
        for (int g = 0; g < 4; ++g)
          acc[m][g] = (f32x4){b1v[g], b1v[g], b1v[g], b1v[g]};
      #pragma unroll
      for (int kt = 0; kt < 8; ++kt){
        short8 am[4];
        #pragma unroll
        for (int m = 0; m < 4; ++m){
          const int arow = m*16 + lidx;
          if (kt < 4)
            am[m] = *(const short8*)&h0rd[sidx(arow, kt*32 + lgrp*8)];
          else
            am[m] = *(const short8*)&h1rd[sidx(arow, (kt-4)*32 + lgrp*8)];
        }
        #pragma unroll
        for (int g = 0; g < 4; ++g){
          short8 wv = *(const short8*)&pw1[(g*8 + kt)*512];
          #pragma unroll
          for (int m = 0; m < 4; ++m)
            acc[m][g] = __builtin_amdgcn_mfma_f32_16x16x32_bf16(am[m], wv, acc[m][g], 0, 0, 0);
        }
      }
      #pragma unroll
      for (int m = 0; m < 4; ++m)
        #pragma unroll
        for (int r = 0; r < 4; ++r){
          float iv = sigf(acc[m][0][r]);
          float fv = sigf(acc[m][1][r]);
          float gv = tanhf_(acc[m][2][r]);
          float ov = sigf(acc[m][3][r]);
          float c = fv*c1[m][r] + iv*gv;
          c1[m][r] = c;
          h1wr[sidx(m*16 + lgrp*4 + r, col)] = f2bf(ov*tanhf_(c));
        }
    }
    BAR();
  }
  // h1[14] lives in hB[0]; uA.h0 dead -> decoder overlay becomes live.

  // ===================== decoder =====================
  const float* dbase = dd;
  const float* hwp   = dd + 1280;
  const float* hbp   = dd + 2048;
  const float* hcp   = dd + 2054;

  float bdv[4];
  #pragma unroll
  for (int g = 0; g < 4; ++g) bdv[g] = bdg[g*128 + col];
  float hwv[6], hbv[6], hcv[6];
  #pragma unroll
  for (int o = 0; o < 6; ++o){
    hwv[o] = hwp[o*128 + col];
    hbv[o] = hbp[o];
    hcv[o] = hcp[o];
  }

  // stage Wp3 + dbase into LDS (uA overlay)
  for (int i = tid; i < 128*4; i += 512){
    int k = i >> 2, o = i & 3;
    uA.d.wp3[k][o] = (o < 3) ? Wp[k*131 + o] : 0.f;
  }
  for (int i = tid; i < 1280; i += 512)
    uA.d.dbl[i >> 7][i & 127] = dbase[i];
  __syncthreads();   // overlay + u2 role switch

  int hcur = 0, hnew = 1;
  #pragma unroll 1
  for (int s = 0; s <= 10; ++s){
    // ---- A: finalize step s-1 (redundant per-lane) / prev0 from x ----
    float prevr[4][3];
    if (s == 0){
      #pragma unroll
      for (int m = 0; m < 4; ++m){
        const int row = m*16 + lidx;
        #pragma unroll
        for (int o = 0; o < 3; ++o)
          prevr[m][o] = x[(size_t)(row0 + row)*90 + 14*6 + o];
      }
    } else {
      const float (*sr)[64][8] = uA.d.sred[(s + 1) & 1];
      #pragma unroll
      for (int m = 0; m < 4; ++m){
        const int row = m*16 + lidx;
        float s1 = 0.f, s2 = 0.f;
        float A0 = 0.f, A1 = 0.f, A2 = 0.f, A3 = 0.f, A4 = 0.f, A5 = 0.f;
        #pragma unroll
        for (int ww = 0; ww < 8; ++ww){
          f32x4 v0 = *(const f32x4*)&sr[ww][row][0];
          f32x4 v1 = *(const f32x4*)&sr[ww][row][4];
          s1 += v0[0]; s2 += v0[1]; A0 += v0[2]; A1 += v0[3];
          A2 += v1[0]; A3 += v1[1]; A4 += v1[2]; A5 += v1[3];
        }
        float mu = s1 * (1.f/128.f);
        float var = s2 * (1.f/128.f) - mu*mu;
        float rs = __builtin_amdgcn_rsqf(var + 1e-5f);
        prevr[m][0] = rs*(A0 - mu*hbv[0]) + hcv[0];
        prevr[m][1] = rs*(A1 - mu*hbv[1]) + hcv[1];
        prevr[m][2] = rs*(A2 - mu*hbv[2]) + hcv[2];
        if (w == 0 && lgrp == 0){
          u2.o.om[row][(s-1)*3 + 0] = prevr[m][0];
          u2.o.om[row][(s-1)*3 + 1] = prevr[m][1];
          u2.o.om[row][(s-1)*3 + 2] = prevr[m][2];
          float q3 = rs*(A3 - mu*hbv[3]) + hcv[3];
          float q4 = rs*(A4 - mu*hbv[4]) + hcv[4];
          float q5 = rs*(A5 - mu*hbv[5]) + hcv[5];
          u2.o.os[row][(s-1)*3 + 0] = fminf(fmaxf(q3, -6.f), 3.f);
          u2.o.os[row][(s-1)*3 + 1] = fminf(fmaxf(q4, -6.f), 3.f);
          u2.o.os[row][(s-1)*3 + 2] = fminf(fmaxf(q5, -6.f), 3.f);
        }
      }
    }

    if (s < 10){
      // ---- B: cell (kt-outer; kt<4 A-frags computed IN-REG from prevr) ----
      const unsigned short* bh = &hB[hcur][0];
      unsigned short* bhn = &hB[hnew][0];
      float (*srw)[64][8] = uA.d.sred[s & 1];

      f32x4 acc[4][4];
      #pragma unroll
      for (int m = 0; m < 4; ++m)
        #pragma unroll
        for (int g = 0; g < 4; ++g)
          acc[m][g] = (f32x4){bdv[g], bdv[g], bdv[g], bdv[g]};
      #pragma unroll
      for (int kt = 0; kt < 8; ++kt){
        short8 am[4];
        if (kt < 4){
          const int k0 = kt*32 + lgrp*8;
          f32x4 db0 = *(const f32x4*)&uA.d.dbl[s][k0];
          f32x4 db1 = *(const f32x4*)&uA.d.dbl[s][k0 + 4];
          f32x4 wpv[8];
          #pragma unroll
          for (int j = 0; j < 8; ++j)
            wpv[j] = *(const f32x4*)&uA.d.wp3[k0 + j][0];
          #pragma unroll
          for (int m = 0; m < 4; ++m){
            short8 a;
            #pragma unroll
            for (int j = 0; j < 8; ++j){
              float db = (j < 4) ? db0[j] : db1[j-4];
              float v = db + prevr[m][0]*wpv[j][0] + prevr[m][1]*wpv[j][1]
                           + prevr[m][2]*wpv[j][2];
              a[j] = (short)f2bf(v > 0.f ? v : 0.f);
            }
            am[m] = a;
          }
        } else {
          #pragma unroll
          for (int m = 0; m < 4; ++m)
            am[m] = *(const short8*)&bh[sidx(m*16 + lidx, (kt-4)*32 + lgrp*8)];
        }
        #pragma unroll
        for (int g = 0; g < 4; ++g){
          short8 wv = *(const short8*)&pw2[(g*8 + kt)*512];
          #pragma unroll
          for (int m = 0; m < 4; ++m)
            acc[m][g] = __builtin_amdgcn_mfma_f32_16x16x32_bf16(am[m], wv, acc[m][g], 0, 0, 0);
        }
      }
      #pragma unroll
      for (int m = 0; m < 4; ++m)
        #pragma unroll
        for (int r = 0; r < 4; ++r){
          float iv = sigf(acc[m][0][r]);
          float fv = sigf(acc[m][1][r]);
          float gv = tanhf_(acc[m][2][r]);
          float ov = sigf(acc[m][3][r]);
          float c = fv*c1[m][r] + iv*gv;
          c1[m][r] = c;
          float h = ov*tanhf_(c);
          const int row = m*16 + lgrp*4 + r;
          bhn[sidx(row, col)] = f2bf(h);
          float vals[8];
          vals[0] = h; vals[1] = h*h;
          #pragma unroll
          for (int o = 0; o < 6; ++o) vals[2+o] = h*hwv[o];
          #pragma unroll
          for (int d = 1; d < 16; d <<= 1)
            #pragma unroll
            for (int kk = 0; kk < 8; ++kk)
              vals[kk] += __shfl_xor(vals[kk], d);
          if (lidx == 0){
            *(f32x4*)&srw[w][row][0] = (f32x4){vals[0], vals[1], vals[2], vals[3]};
            *(f32x4*)&srw[w][row][4] = (f32x4){vals[4], vals[5], vals[6], vals[7]};
          }
        }
      BAR();
      int tswap = hcur; hcur = hnew; hnew = tswap;
    }
  }

  __syncthreads();
  // ---- single coalesced output flush ----
  for (int i = tid; i < 1920; i += 512){
    int r = i / 30, cx = i - r*30;
    out[(size_t)(row0 + r)*30 + cx] = u2.o.om[r][cx];
    out[(size_t)65536*30 + (size_t)(row0 + r)*30 + cx] = u2.o.os[r][cx];
  }
}

extern "C" void kernel_launch(void* const* d_in, const int* in_sizes, int n_in,
                              void* d_out, int out_size, void* d_ws, size_t ws_size,
                              hipStream_t stream)
{
  const float* x    = (const float*)d_in[0];
  const float* Wih0 = (const float*)d_in[1];
  const float* Whh0 = (const float*)d_in[2];
  const float* b0   = (const float*)d_in[3];
  const float* Wih1 = (const float*)d_in[4];
  const float* Whh1 = (const float*)d_in[5];
  const float* b1   = (const float*)d_in[6];
  const float* Wihd = (const float*)d_in[7];
  const float* Whhd = (const float*)d_in[8];
  const float* bd   = (const float*)d_in[9];
  const float* emb  = (const float*)d_in[10];
  const float* Wp   = (const float*)d_in[11];
  const float* bp   = (const float*)d_in[12];
  const float* Wm   = (const float*)d_in[13];
  const float* bm   = (const float*)d_in[14];
  const float* Ws   = (const float*)d_in[15];
  const float* bs   = (const float*)d_in[16];
  const float* lng  = (const float*)d_in[17];
  const float* lnb  = (const float*)d_in[18];

  unsigned short* pkw = (unsigned short*)d_ws;
  float* dd = (float*)((char*)d_ws + DD_OFF);

  pack_w<<<(PK_TOTAL + 255)/256, 256, 0, stream>>>(Wih0, Whh0, Wih1, Whh1,
                                                   Wihd, Whhd, Wm, Ws, pkw);
  prep_dec<<<17, 128, 0, stream>>>(emb, Wp, bp, Wm, Ws, bm, bs, lng, lnb, dd);
  traj_main<<<1024, 512, 0, stream>>>(x, pkw, dd, b0, b1, bd, Wp, (float*)d_out);
}